// Round 2
// baseline (234.097 us; speedup 1.0000x reference)
//
#include <hip/hip_runtime.h>

typedef __attribute__((ext_vector_type(8))) short short8;
typedef __attribute__((ext_vector_type(4))) float f32x4;

// ---- problem constants ----
#define NSPAN 1024
#define DDIM  512
#define HDIM  150
#define HPAD  160
#define WINW  250
#define OUTW  251

// ---- LDS layout (main kernel), bytes ----
// A2 (h1 bf16 [128][160], row stride 320B, swizzle (row&3)<<4): [0, 40960)
// A1 (prod bf16 [128][32], row stride 64B, swizzle ((r>>1)&7)<<4): [40960, 49152)
// B1t (W1c^T chunk bf16 [160][32], 64B rows, same swizzle):       [49152, 59392)
// gi  (g_i row f32 [512]):                                        [59392, 61440)
// B2t chunk aliases A1/B1 region at 40960 during GEMM2.
// sL  (f32 [128]):                                                [61440, 61952)
#define A1_OFF 40960
#define B1_OFF 49152
#define GI_OFF 59392
#define B2_OFF 40960
#define S_OFF  61440
#define SMEM_BYTES 61952

__device__ __forceinline__ unsigned short f2bf(float x) {
  union { float f; unsigned int u; } v; v.f = x;
  return (unsigned short)((v.u + 0x7fffu + ((v.u >> 16) & 1u)) >> 16);
}
__device__ __forceinline__ unsigned int pk2(float a, float b) {
  return (unsigned int)f2bf(a) | ((unsigned int)f2bf(b) << 16);
}

// ---------------- prep: pre1 = g@W1a + b1, gjb = g@W1b (fp32) ----------------
// grid: 256 blocks = 128 i-groups(8 rows) x 2 (which), block 192 threads
__global__ __launch_bounds__(192) void prep_gemm(
    const float* __restrict__ g, const float* __restrict__ W1,
    const float* __restrict__ b1, float* __restrict__ pre1,
    float* __restrict__ gjb)
{
  __shared__ __align__(16) float gs[8 * DDIM];
  const int grp = blockIdx.x >> 1;
  const int which = blockIdx.x & 1;
  const int i0 = grp << 3;
  for (int idx = threadIdx.x; idx < (8 * DDIM / 4); idx += 192)
    ((float4*)gs)[idx] = ((const float4*)(g + (size_t)i0 * DDIM))[idx];
  __syncthreads();
  const int n = threadIdx.x;
  float acc[8];
#pragma unroll
  for (int r = 0; r < 8; ++r) acc[r] = 0.f;
  if (n < HDIM) {
    const float* Wp = W1 + (size_t)which * DDIM * HDIM + n;
#pragma unroll 4
    for (int d = 0; d < DDIM; ++d) {
      float w = Wp[(size_t)d * HDIM];
#pragma unroll
      for (int r = 0; r < 8; ++r) acc[r] += gs[r * DDIM + d] * w;
    }
  }
  if (n < HPAD) {
    float* dst = which ? gjb : pre1;
    float add = (which == 0 && n < HDIM) ? b1[n] : 0.f;
#pragma unroll
    for (int r = 0; r < 8; ++r)
      dst[(size_t)(i0 + r) * HPAD + n] = (n < HDIM) ? (acc[r] + add) : 0.f;
  }
}

// ---------------- prep: transpose + bf16 convert W1c, W2; pad W3 ----------------
// w1cT[n][d] (160x512 bf16), w2T[n][k] (160x160 bf16), w3p[160] f32
__global__ void prep_misc(const float* __restrict__ W1, const float* __restrict__ W2,
                          const float* __restrict__ W3,
                          unsigned short* __restrict__ w1cT,
                          unsigned short* __restrict__ w2T,
                          float* __restrict__ w3p)
{
  int id = blockIdx.x * 256 + threadIdx.x;
  if (id < HPAD * DDIM) {                       // 81920
    int n = id >> 9, d = id & 511;
    float v = (n < HDIM) ? W1[(size_t)(2 * DDIM + d) * HDIM + n] : 0.f;
    w1cT[id] = f2bf(v);
  } else if (id < HPAD * DDIM + HPAD * HPAD) {  // +25600
    int id2 = id - HPAD * DDIM;
    int n = id2 / HPAD, k = id2 % HPAD;
    float v = (n < HDIM && k < HDIM) ? W2[(size_t)k * HDIM + n] : 0.f;
    w2T[id2] = f2bf(v);
  } else if (id < HPAD * DDIM + HPAD * HPAD + HPAD) {
    int n = id - HPAD * DDIM - HPAD * HPAD;
    w3p[n] = (n < HDIM) ? W3[n] : 0.f;
  }
}

// ---------------- main fused kernel ----------------
// block = (i, half): 128 window rows. 4 waves, each owns rows [wv*32, wv*32+32).
__global__ __launch_bounds__(256, 2) void pair_main(
    const float* __restrict__ g, const float* __restrict__ sm,
    const float* __restrict__ pre1, const float* __restrict__ gjb,
    const unsigned short* __restrict__ w1cT, const unsigned short* __restrict__ w2T,
    const float* __restrict__ w3p, const float* __restrict__ b2,
    const float* __restrict__ b3, float* __restrict__ out)
{
  __shared__ __align__(16) char smem[SMEM_BYTES];
  const int tid = threadIdx.x;
  const int lane = tid & 63;
  const int wv = tid >> 6;
  const int l15 = lane & 15;
  const int lq = lane >> 4;          // 0..3
  const int i = blockIdx.x >> 1;
  const int mbase = (blockIdx.x & 1) << 7;

  // stage g_i row (512 f32) into LDS
  float* giL = (float*)(smem + GI_OFF);
  if (tid < 128)
    ((float4*)giL)[tid] = ((const float4*)(g + (size_t)i * DDIM))[tid];

  // A1 staging setup: thread -> (row, 16-col half)
  const int r_s = tid >> 1;
  const int kh = (tid & 1) << 4;     // 0 or 16
  const int rg_s = mbase + r_s;
  const int j_s = i - WINW + rg_s;
  const bool val_s = (rg_s < WINW) && (j_s >= 0);
  const int jc_s = j_s < 0 ? 0 : (j_s > NSPAN - 1 ? NSPAN - 1 : j_s);
  const float4* gj4 = (const float4*)(g + (size_t)jc_s * DDIM);
  const int swA = ((r_s >> 1) & 7) << 4;
  const int stA0 = A1_OFF + (((r_s << 6) + (kh << 1)) ^ swA);
  const int stA1 = A1_OFF + (((r_s << 6) + (kh << 1) + 16) ^ swA);

  // fragment read addresses (64B-stride buffers, pair-XOR swizzle)
  int xa[2];
#pragma unroll
  for (int mt = 0; mt < 2; ++mt) {
    int row = (wv << 5) + (mt << 4) + l15;
    xa[mt] = ((row << 6) + (lq << 4)) ^ (((row >> 1) & 7) << 4);
  }
  int xb[10];
#pragma unroll
  for (int nt = 0; nt < 10; ++nt) {
    int nr = (nt << 4) + l15;
    xb[nt] = ((nr << 6) + (lq << 4)) ^ (((nr >> 1) & 7) << 4);
  }

  f32x4 acc[2][10];
#pragma unroll
  for (int mt = 0; mt < 2; ++mt)
#pragma unroll
    for (int nt = 0; nt < 10; ++nt)
      acc[mt][nt] = (f32x4){0.f, 0.f, 0.f, 0.f};

  __syncthreads();   // giL ready

  // ---- GEMM1: [128 x 512] (g_i*g_j bf16) @ [512 x 160] (W1c) ----
  for (int k0 = 0; k0 < DDIM; k0 += 32) {
    { // stage A1: products -> bf16, swizzled
      const int fb = (k0 + kh) >> 2;
      float4 x0 = gj4[fb], x1 = gj4[fb + 1], x2 = gj4[fb + 2], x3 = gj4[fb + 3];
      const float4* gi4 = ((const float4*)giL) + fb;
      float4 y0 = gi4[0], y1 = gi4[1], y2 = gi4[2], y3 = gi4[3];
      uint4 w0, w1;
      w0.x = pk2(x0.x * y0.x, x0.y * y0.y);
      w0.y = pk2(x0.z * y0.z, x0.w * y0.w);
      w0.z = pk2(x1.x * y1.x, x1.y * y1.y);
      w0.w = pk2(x1.z * y1.z, x1.w * y1.w);
      w1.x = pk2(x2.x * y2.x, x2.y * y2.y);
      w1.y = pk2(x2.z * y2.z, x2.w * y2.w);
      w1.z = pk2(x3.x * y3.x, x3.y * y3.y);
      w1.w = pk2(x3.z * y3.z, x3.w * y3.w);
      if (!val_s) { w0 = make_uint4(0, 0, 0, 0); w1 = make_uint4(0, 0, 0, 0); }
      *(uint4*)(smem + stA0) = w0;
      *(uint4*)(smem + stA1) = w1;
    }
    // stage B1t chunk: w1cT[n][k0..k0+32)
#pragma unroll
    for (int q = 0; q < 3; ++q) {
      int ch = tid + (q << 8);
      if (ch < 640) {
        int n = ch >> 2, sl = ch & 3;
        uint4 v = *(const uint4*)(w1cT + (size_t)n * DDIM + k0 + (sl << 3));
        *(uint4*)(smem + B1_OFF + (((n << 6) + (sl << 4)) ^ (((n >> 1) & 7) << 4))) = v;
      }
    }
    __syncthreads();
    short8 a0 = *(const short8*)(smem + A1_OFF + xa[0]);
    short8 a1 = *(const short8*)(smem + A1_OFF + xa[1]);
#pragma unroll
    for (int nt = 0; nt < 10; ++nt) {
      short8 bb = *(const short8*)(smem + B1_OFF + xb[nt]);
      acc[0][nt] = __builtin_amdgcn_mfma_f32_16x16x32_bf16(a0, bb, acc[0][nt], 0, 0, 0);
      acc[1][nt] = __builtin_amdgcn_mfma_f32_16x16x32_bf16(a1, bb, acc[1][nt], 0, 0, 0);
    }
    __syncthreads();
  }

  // ---- epilogue 1: h1 = relu(acc + pre1_i + gjb_j) -> A2 (bf16, swizzled) ----
  float p1v[10];
#pragma unroll
  for (int nt = 0; nt < 10; ++nt)
    p1v[nt] = pre1[(size_t)i * HPAD + (nt << 4) + l15];

#pragma unroll
  for (int mt = 0; mt < 2; ++mt) {
#pragma unroll
    for (int rr = 0; rr < 4; ++rr) {
      const int row = (wv << 5) + (mt << 4) + (lq << 2) + rr;
      const int rgl = mbase + row;
      int j = i - WINW + rgl;
      j = j < 0 ? 0 : (j > NSPAN - 1 ? NSPAN - 1 : j);
      const float* gjr = gjb + (size_t)j * HPAD;
      const int sw = (row & 3) << 4;
      const int rb = row * 320;
#pragma unroll
      for (int nt = 0; nt < 10; ++nt) {
        float v = acc[mt][nt][rr] + p1v[nt] + gjr[(nt << 4) + l15];
        v = fmaxf(v, 0.f);
        *(unsigned short*)(smem + ((rb + (((nt << 4) + l15) << 1)) ^ sw)) = f2bf(v);
      }
    }
  }

  // ---- GEMM2: [128 x 160] (h1) @ [160 x 160] (W2), K chunks of 32 ----
  f32x4 acc2[2][10];
#pragma unroll
  for (int mt = 0; mt < 2; ++mt)
#pragma unroll
    for (int nt = 0; nt < 10; ++nt)
      acc2[mt][nt] = (f32x4){0.f, 0.f, 0.f, 0.f};

  int ya[2];
#pragma unroll
  for (int mt = 0; mt < 2; ++mt) {
    int row = (wv << 5) + (mt << 4) + l15;
    ya[mt] = ((row * 320) + (lq << 4)) ^ ((row & 3) << 4);
  }

  for (int c = 0; c < 5; ++c) {
#pragma unroll
    for (int q = 0; q < 3; ++q) {
      int ch = tid + (q << 8);
      if (ch < 640) {
        int n = ch >> 2, sl = ch & 3;
        uint4 v = *(const uint4*)(w2T + (size_t)n * HPAD + (c << 5) + (sl << 3));
        *(uint4*)(smem + B2_OFF + (((n << 6) + (sl << 4)) ^ (((n >> 1) & 7) << 4))) = v;
      }
    }
    __syncthreads();
    short8 a0 = *(const short8*)(smem + ya[0] + (c << 6));
    short8 a1 = *(const short8*)(smem + ya[1] + (c << 6));
#pragma unroll
    for (int nt = 0; nt < 10; ++nt) {
      short8 bb = *(const short8*)(smem + B2_OFF + xb[nt]);
      acc2[0][nt] = __builtin_amdgcn_mfma_f32_16x16x32_bf16(a0, bb, acc2[0][nt], 0, 0, 0);
      acc2[1][nt] = __builtin_amdgcn_mfma_f32_16x16x32_bf16(a1, bb, acc2[1][nt], 0, 0, 0);
    }
    __syncthreads();
  }

  // ---- GEMM3: s = relu(acc2 + b2) @ W3, 16-lane shuffle reduce ----
  float w3v[10], b2v[10];
#pragma unroll
  for (int nt = 0; nt < 10; ++nt) {
    int nn = (nt << 4) + l15;
    w3v[nt] = w3p[nn];
    b2v[nt] = (nn < HDIM) ? b2[nn] : 0.f;
  }
  float* sL = (float*)(smem + S_OFF);
#pragma unroll
  for (int mt = 0; mt < 2; ++mt) {
#pragma unroll
    for (int rr = 0; rr < 4; ++rr) {
      float part = 0.f;
#pragma unroll
      for (int nt = 0; nt < 10; ++nt) {
        float h2 = fmaxf(acc2[mt][nt][rr] + b2v[nt], 0.f);
        part = fmaf(h2, w3v[nt], part);
      }
      part += __shfl_xor(part, 1);
      part += __shfl_xor(part, 2);
      part += __shfl_xor(part, 4);
      part += __shfl_xor(part, 8);
      if (l15 == 0)
        sL[(wv << 5) + (mt << 4) + (lq << 2) + rr] = part;
    }
  }
  __syncthreads();

  // ---- final: sij = sm_i + sm_j + s + b3, masked; epsilon col = 0 ----
  if (tid < 128) {
    const int rg = mbase + tid;
    if (rg <= WINW) {
      const int j = i - WINW + rg;
      float v = 0.f;
      if (rg < WINW && j >= 0)
        v = sL[tid] + b3[0] + sm[i] + sm[j];
      out[(size_t)i * OUTW + rg] = v;
    }
  }
}

extern "C" void kernel_launch(void* const* d_in, const int* in_sizes, int n_in,
                              void* d_out, int out_size, void* d_ws, size_t ws_size,
                              hipStream_t stream) {
  const float* g  = (const float*)d_in[0];
  const float* sm = (const float*)d_in[1];
  const float* W1 = (const float*)d_in[2];
  const float* b1 = (const float*)d_in[3];
  const float* W2 = (const float*)d_in[4];
  const float* b2 = (const float*)d_in[5];
  const float* W3 = (const float*)d_in[6];
  const float* b3 = (const float*)d_in[7];
  float* out = (float*)d_out;

  // workspace carve (total 1,526,400 B)
  char* ws = (char*)d_ws;
  float* pre1          = (float*)ws;                         // 1024*160*4 = 655360
  float* gjb           = (float*)(ws + 655360);              // 655360
  unsigned short* w1cT = (unsigned short*)(ws + 1310720);    // 160*512*2 = 163840
  unsigned short* w2T  = (unsigned short*)(ws + 1474560);    // 160*160*2 = 51200
  float* w3p           = (float*)(ws + 1525760);             // 640

  prep_gemm<<<256, 192, 0, stream>>>(g, W1, b1, pre1, gjb);
  prep_misc<<<(HPAD * DDIM + HPAD * HPAD + HPAD + 255) / 256, 256, 0, stream>>>(
      W1, W2, W3, w1cT, w2T, w3p);
  pair_main<<<2048, 256, 0, stream>>>(g, sm, pre1, gjb, w1cT, w2T, w3p, b2, b3, out);
}